// Round 4
// baseline (609.109 us; speedup 1.0000x reference)
//
#include <hip/hip_runtime.h>
#include <stdint.h>

#define BATCH 8
#define L_SEQ 2048
#define D_MODEL 512
#define TOPK 7
#define BM 128
#define BN 128
#define BK 32
#define LK 40   // LDS row stride in f16 elems for ds_write-staged GEMM

typedef _Float16 f16x8 __attribute__((ext_vector_type(8)));
typedef __attribute__((ext_vector_type(4))) float f32x4;
typedef unsigned short u16;
typedef unsigned int u32;

__device__ __forceinline__ u16 f2h(float f) {
    union { _Float16 h; u16 u; } v; v.h = (_Float16)f; return v.u;
}
__device__ __forceinline__ float h2f(u16 b) {
    union { u16 u; _Float16 h; } v; v.u = b; return (float)v.h;
}

// async 16B/lane global->LDS (m97). Dest = wave-uniform base + lane*16.
__device__ __forceinline__ void load_lds16(const u16* g, u16* l) {
    __builtin_amdgcn_global_load_lds(
        (const __attribute__((address_space(1))) u32*)(g),
        (__attribute__((address_space(3))) u32*)(l), 16, 0, 0);
}

// ---------------- QKV projection GEMM: A fp32 (convert in staging), C f16 ----------------
// C = A * B^T + bias.  A: M x K fp32.  Bt: N x K f16.
__global__ __launch_bounds__(256) void gemm_a32(
    const float* __restrict__ A, const u16* __restrict__ Bt,
    const float* __restrict__ bias, u16* __restrict__ C, int N, int K)
{
    __shared__ __align__(16) u16 lA[BM * LK];
    __shared__ __align__(16) u16 lB[BN * LK];

    const int tid = threadIdx.x;
    const int bn = blockIdx.x, bm = blockIdx.y;
    const int lane = tid & 63, wave = tid >> 6;
    const int wm = wave >> 1, wn = wave & 1;
    const int l15 = lane & 15, quad = lane >> 4;

    f32x4 acc[4][4] = {};

    for (int k0 = 0; k0 < K; k0 += BK) {
        #pragma unroll
        for (int j = 0; j < 4; ++j) {
            int idx = tid + j * 256;                  // 128x32 tile / 4
            int row = idx >> 3, c4 = (idx & 7) * 4;
            float4 va = *(const float4*)(A + (long)(bm * BM + row) * K + k0 + c4);
            ushort4 pa;
            pa.x = f2h(va.x); pa.y = f2h(va.y); pa.z = f2h(va.z); pa.w = f2h(va.w);
            *(ushort4*)&lA[row * LK + c4] = pa;
        }
        #pragma unroll
        for (int j = 0; j < 2; ++j) {
            int idx = tid + j * 256;                  // 128x32 tile / 8
            int row = idx >> 2, c8 = (idx & 3) * 8;
            *(uint4*)&lB[row * LK + c8] =
                *(const uint4*)(Bt + (long)(bn * BN + row) * K + k0 + c8);
        }
        __syncthreads();

        f16x8 fa[4], fb[4];
        #pragma unroll
        for (int i = 0; i < 4; ++i)
            fa[i] = *(const f16x8*)&lA[(wm * 64 + i * 16 + l15) * LK + quad * 8];
        #pragma unroll
        for (int j = 0; j < 4; ++j)
            fb[j] = *(const f16x8*)&lB[(wn * 64 + j * 16 + l15) * LK + quad * 8];
        #pragma unroll
        for (int i = 0; i < 4; ++i)
            #pragma unroll
            for (int j = 0; j < 4; ++j)
                acc[i][j] = __builtin_amdgcn_mfma_f32_16x16x32_f16(fa[i], fb[j], acc[i][j], 0, 0, 0);
        __syncthreads();
    }

    #pragma unroll
    for (int i = 0; i < 4; ++i) {
        int row = bm * BM + wm * 64 + i * 16 + quad * 4;
        #pragma unroll
        for (int j = 0; j < 4; ++j) {
            int col = bn * BN + wn * 64 + j * 16 + l15;
            float bvv = bias[col];
            #pragma unroll
            for (int r = 0; r < 4; ++r)
                C[(long)(row + r) * N + col] = f2h(acc[i][j][r] + bvv);
        }
    }
}

// ---------------- final projection GEMM: A f16 via global_load_lds, C fp32 ----------------
__global__ __launch_bounds__(256, 4) void gemm_f16_out32(
    const u16* __restrict__ A, const u16* __restrict__ Bt,
    const float* __restrict__ bias, float* __restrict__ Cp, int N, int K)
{
    __shared__ __align__(16) u16 lA[BM * BK];   // 8 KB, unpadded, XOR-swizzled
    __shared__ __align__(16) u16 lB[BN * BK];

    const int tid = threadIdx.x;
    const int bn = blockIdx.x, bm = blockIdx.y;
    const int lane = tid & 63, wave = tid >> 6;
    const int wm = wave >> 1, wn = wave & 1;
    const int l15 = lane & 15, quad = lane >> 4;

    const int s0 = wave * 64 + lane, s1 = s0 + 256;
    const int r0 = s0 >> 2, c0 = (s0 & 3) ^ ((r0 >> 1) & 3);
    const int r1 = s1 >> 2, c1 = (s1 & 3) ^ ((r1 >> 1) & 3);
    const u16* gA0 = A + (long)(bm * BM + r0) * K + c0 * 8;
    const u16* gA1 = A + (long)(bm * BM + r1) * K + c1 * 8;
    const u16* gB0 = Bt + (long)(bn * BN + r0) * K + c0 * 8;
    const u16* gB1 = Bt + (long)(bn * BN + r1) * K + c1 * 8;
    u16* lA0 = &lA[wave * 512]; u16* lA1 = &lA[2048 + wave * 512];
    u16* lB0 = &lB[wave * 512]; u16* lB1 = &lB[2048 + wave * 512];

    f32x4 acc[4][4] = {};

    for (int k0 = 0; k0 < K; k0 += BK) {
        load_lds16(gA0, lA0); load_lds16(gA1, lA1);
        load_lds16(gB0, lB0); load_lds16(gB1, lB1);
        gA0 += BK; gA1 += BK; gB0 += BK; gB1 += BK;
        __syncthreads();

        f16x8 fa[4], fb[4];
        #pragma unroll
        for (int i = 0; i < 4; ++i) {
            int m = wm * 64 + i * 16 + l15;
            int cs = quad ^ ((m >> 1) & 3);
            fa[i] = *(const f16x8*)&lA[m * 32 + cs * 8];
        }
        #pragma unroll
        for (int j = 0; j < 4; ++j) {
            int n = wn * 64 + j * 16 + l15;
            int cs = quad ^ ((n >> 1) & 3);
            fb[j] = *(const f16x8*)&lB[n * 32 + cs * 8];
        }
        #pragma unroll
        for (int i = 0; i < 4; ++i)
            #pragma unroll
            for (int j = 0; j < 4; ++j)
                acc[i][j] = __builtin_amdgcn_mfma_f32_16x16x32_f16(fa[i], fb[j], acc[i][j], 0, 0, 0);
        __syncthreads();
    }

    #pragma unroll
    for (int i = 0; i < 4; ++i) {
        int row = bm * BM + wm * 64 + i * 16 + quad * 4;
        #pragma unroll
        for (int j = 0; j < 4; ++j) {
            int col = bn * BN + wn * 64 + j * 16 + l15;
            float bvv = bias[col];
            #pragma unroll
            for (int r = 0; r < 4; ++r)
                Cp[(long)(row + r) * N + col] = acc[i][j][r] + bvv;
        }
    }
}

// ---------------- FFT autocorrelation ----------------
// Packed trick: z[t] = q[b,t,d] + i*k[b,t,d]; one 2048-pt complex FFT recovers
// Qhat, Khat; accumulate S[b,f] += Qhat*conj(Khat) over this block's 8 d-channels.
__global__ __launch_bounds__(256) void fft_corr_fwd(
    const u16* __restrict__ Qf, const u16* __restrict__ Kf, float* __restrict__ S)
{
    __shared__ float2 Z[2048];      // 16 KB
    __shared__ float2 Tw[1024];     // 8 KB twiddles
    __shared__ float2 Sacc[2048];   // 16 KB
    const int tid = threadIdx.x;
    const int b = blockIdx.x >> 6, dg = blockIdx.x & 63;

    #pragma unroll
    for (int j = 0; j < 4; ++j) {
        int i = tid + j * 256;
        float ang = -6.28318530717958647692f * (float)i * (1.0f / 2048.0f);
        float sn, cs; __sincosf(ang, &sn, &cs);
        Tw[i] = make_float2(cs, sn);
    }
    #pragma unroll
    for (int j = 0; j < 8; ++j) Sacc[tid + j * 256] = make_float2(0.f, 0.f);

    const u16* qb = Qf + (long)b * L_SEQ * D_MODEL;
    const u16* kb = Kf + (long)b * L_SEQ * D_MODEL;

    for (int g = 0; g < 8; ++g) {
        int d = dg * 8 + g;
        __syncthreads();   // Z reused: previous extraction read Z
        #pragma unroll
        for (int j = 0; j < 8; ++j) {
            int t = tid + j * 256;
            int tr = (int)(__brev((unsigned)t) >> 21);   // 11-bit reversal
            Z[tr] = make_float2(h2f(qb[(long)t * D_MODEL + d]),
                                h2f(kb[(long)t * D_MODEL + d]));
        }
        __syncthreads();
        for (int s = 0; s < 11; ++s) {
            #pragma unroll
            for (int j = 0; j < 4; ++j) {
                int idx = tid + j * 256;
                int pos = idx & ((1 << s) - 1);
                int i0 = ((idx >> s) << (s + 1)) + pos;
                int i1 = i0 + (1 << s);
                float2 w = Tw[pos << (10 - s)];
                float2 a = Z[i0], bb = Z[i1];
                float br = bb.x * w.x - bb.y * w.y;
                float bi = bb.x * w.y + bb.y * w.x;
                Z[i0] = make_float2(a.x + br, a.y + bi);
                Z[i1] = make_float2(a.x - br, a.y - bi);
            }
            __syncthreads();
        }
        #pragma unroll
        for (int j = 0; j < 8; ++j) {
            int f = tid + j * 256;
            int fm = (2048 - f) & 2047;
            float2 X = Z[f], Xm = Z[fm];
            float qr = 0.5f * (X.x + Xm.x), qi = 0.5f * (X.y - Xm.y);   // Qhat
            float dr = X.x - Xm.x,          di = X.y + Xm.y;            // X - conj(Xm)
            float kr = 0.5f * di,           ki = -0.5f * dr;            // Khat = -0.5i*D
            float pr = qr * kr + qi * ki;                               // Qhat*conj(Khat)
            float pi = qi * kr - qr * ki;
            float2 sv = Sacc[f];
            Sacc[f] = make_float2(sv.x + pr, sv.y + pi);
        }
    }
    __syncthreads();
    #pragma unroll
    for (int j = 0; j < 8; ++j) {
        int f = tid + j * 256;
        atomicAdd(&S[((long)b * 2048 + f) * 2 + 0], Sacc[f].x);
        atomicAdd(&S[((long)b * 2048 + f) * 2 + 1], Sacc[f].y);
    }
}

// raw[b][tau] = (1/2048) * Re( IFFT(S[b]) )  — one block per b
__global__ __launch_bounds__(256) void fft_corr_inv(
    const float* __restrict__ S, float* __restrict__ raw)
{
    __shared__ float2 Z[2048];
    __shared__ float2 Tw[1024];
    const int tid = threadIdx.x;
    const int b = blockIdx.x;

    #pragma unroll
    for (int j = 0; j < 4; ++j) {
        int i = tid + j * 256;
        float ang = 6.28318530717958647692f * (float)i * (1.0f / 2048.0f);
        float sn, cs; __sincosf(ang, &sn, &cs);
        Tw[i] = make_float2(cs, sn);
    }
    #pragma unroll
    for (int j = 0; j < 8; ++j) {
        int f = tid + j * 256;
        int fr = (int)(__brev((unsigned)f) >> 21);
        Z[fr] = make_float2(S[((long)b * 2048 + f) * 2 + 0],
                            S[((long)b * 2048 + f) * 2 + 1]);
    }
    __syncthreads();
    for (int s = 0; s < 11; ++s) {
        #pragma unroll
        for (int j = 0; j < 4; ++j) {
            int idx = tid + j * 256;
            int pos = idx & ((1 << s) - 1);
            int i0 = ((idx >> s) << (s + 1)) + pos;
            int i1 = i0 + (1 << s);
            float2 w = Tw[pos << (10 - s)];
            float2 a = Z[i0], bb = Z[i1];
            float br = bb.x * w.x - bb.y * w.y;
            float bi = bb.x * w.y + bb.y * w.x;
            Z[i0] = make_float2(a.x + br, a.y + bi);
            Z[i1] = make_float2(a.x - br, a.y - bi);
        }
        __syncthreads();
    }
    #pragma unroll
    for (int j = 0; j < 8; ++j) {
        int t = tid + j * 256;
        raw[(long)b * 2048 + t] = Z[t].x * (1.0f / 2048.0f);
    }
}

// Wt[n][k] = W[k][n], fp32 -> fp16
__global__ __launch_bounds__(256) void transposeW(const float* __restrict__ src, u16* __restrict__ dst)
{
    __shared__ float t[32][33];
    int tx = threadIdx.x & 31, ty = threadIdx.x >> 5;
    int c0 = blockIdx.x * 32, r0 = blockIdx.y * 32;
    #pragma unroll
    for (int r = ty; r < 32; r += 8)
        t[r][tx] = src[(long)(r0 + r) * D_MODEL + c0 + tx];
    __syncthreads();
    #pragma unroll
    for (int r = ty; r < 32; r += 8)
        dst[(long)(c0 + r) * D_MODEL + r0 + tx] = f2h(t[tx][r]);
}

// One block. g[tau] = sum_b raw[b][tau]; top-7; per-b softmax of raw[b][idx]/512.
__global__ __launch_bounds__(256) void select_topk(
    const float* __restrict__ raw, int* __restrict__ selIdx, float* __restrict__ selW)
{
    __shared__ float g[L_SEQ];
    __shared__ float rv[256];
    __shared__ int   ri[256];
    __shared__ int   sidx[TOPK];
    __shared__ float wbuf[BATCH][TOPK];
    int tid = threadIdx.x;
    for (int t = tid; t < L_SEQ; t += 256) {
        float s = 0.0f;
        #pragma unroll
        for (int b = 0; b < BATCH; ++b) s += raw[b * L_SEQ + t];
        g[t] = s;
    }
    __syncthreads();
    for (int it = 0; it < TOPK; ++it) {
        float best = -1e30f; int bi = 0x7fffffff;
        for (int t = tid; t < L_SEQ; t += 256) {
            float v = g[t];
            if (v > best || (v == best && t < bi)) { best = v; bi = t; }
        }
        rv[tid] = best; ri[tid] = bi;
        __syncthreads();
        for (int s = 128; s > 0; s >>= 1) {
            if (tid < s) {
                float v2 = rv[tid + s]; int i2 = ri[tid + s];
                if (v2 > rv[tid] || (v2 == rv[tid] && i2 < ri[tid])) { rv[tid] = v2; ri[tid] = i2; }
            }
            __syncthreads();
        }
        if (tid == 0) { sidx[it] = ri[0]; g[ri[0]] = -1e30f; }
        __syncthreads();
    }
    if (tid < BATCH * TOPK) {
        int b = tid / TOPK, k = tid % TOPK;
        wbuf[b][k] = raw[b * L_SEQ + sidx[k]] * (1.0f / 512.0f);
    }
    __syncthreads();
    if (tid < BATCH) {
        float mx = -1e30f;
        #pragma unroll
        for (int k = 0; k < TOPK; ++k) mx = fmaxf(mx, wbuf[tid][k]);
        float e[TOPK]; float sum = 0.0f;
        #pragma unroll
        for (int k = 0; k < TOPK; ++k) { e[k] = expf(wbuf[tid][k] - mx); sum += e[k]; }
        #pragma unroll
        for (int k = 0; k < TOPK; ++k) selW[tid * TOPK + k] = e[k] / sum;
    }
    if (tid < TOPK) selIdx[tid] = sidx[tid];
}

// attn[b,l,:] = sum_k w[b][k] * V[b,(l+idx[k])%L,:]  (f16 in/out, 8 elems/thread)
__global__ __launch_bounds__(256) void gather_agg(
    const u16* __restrict__ V, const int* __restrict__ selIdx,
    const float* __restrict__ selW, u16* __restrict__ outB)
{
    __shared__ int si[TOPK];
    __shared__ float sw[TOPK];
    long flat = (long)blockIdx.x * 256 + threadIdx.x;     // over B*L*D/8 uint4s
    int b  = (int)(flat >> 17);
    int l  = (int)((flat >> 6) & (L_SEQ - 1));
    int d8 = (int)(flat & 63);
    if (threadIdx.x < TOPK) {
        si[threadIdx.x] = selIdx[threadIdx.x];
        sw[threadIdx.x] = selW[b * TOPK + threadIdx.x];
    }
    __syncthreads();
    const uint4* v8 = (const uint4*)(V + (long)b * L_SEQ * D_MODEL);
    float a[8] = {0,0,0,0,0,0,0,0};
    #pragma unroll
    for (int k = 0; k < TOPK; ++k) {
        int src = (l + si[k]) & (L_SEQ - 1);
        union { uint4 u; _Float16 h[8]; } x;
        x.u = v8[src * 64 + d8];
        float w = sw[k];
        #pragma unroll
        for (int q = 0; q < 8; ++q) a[q] += w * (float)x.h[q];
    }
    union { uint4 u; _Float16 h[8]; } o;
    #pragma unroll
    for (int q = 0; q < 8; ++q) o.h[q] = (_Float16)a[q];
    ((uint4*)outB)[flat] = o.u;
}

extern "C" void kernel_launch(void* const* d_in, const int* in_sizes, int n_in,
                              void* d_out, int out_size, void* d_ws, size_t ws_size,
                              hipStream_t stream)
{
    (void)in_sizes; (void)n_in; (void)out_size; (void)ws_size;
    const float* Xq = (const float*)d_in[0];
    const float* Xk = (const float*)d_in[1];
    const float* Xv = (const float*)d_in[2];
    const float* Wq = (const float*)d_in[3];
    const float* bq = (const float*)d_in[4];
    const float* Wk = (const float*)d_in[5];
    const float* bk = (const float*)d_in[6];
    const float* Wv = (const float*)d_in[7];
    const float* bv = (const float*)d_in[8];
    const float* Wo = (const float*)d_in[9];
    const float* bo = (const float*)d_in[10];

    char* ws = (char*)d_ws;
    const long SLABH = (long)BATCH * L_SEQ * D_MODEL * sizeof(u16);   // 16 MB
    u16* Qf   = (u16*)(ws);
    u16* Kf   = (u16*)(ws + SLABH);
    u16* Vf   = (u16*)(ws + 2 * SLABH);
    u16* attn = (u16*)(ws + 3 * SLABH);
    const long WSZ = (long)D_MODEL * D_MODEL;
    u16* Wt   = (u16*)(ws + 4 * SLABH);        // 4 x 512 KB
    u16* Wqt = Wt + 0 * WSZ; u16* Wkt = Wt + 1 * WSZ;
    u16* Wvt = Wt + 2 * WSZ; u16* Wot = Wt + 3 * WSZ;
    float* S   = (float*)(ws + 4 * SLABH + 4 * WSZ * sizeof(u16));   // 8*2048*2 fp32
    float* raw = S + (long)BATCH * L_SEQ * 2;
    int*   sIdx = (int*)(raw + (long)BATCH * L_SEQ);
    float* sW   = (float*)(sIdx + 8);

    dim3 tb(256);
    transposeW<<<dim3(16, 16), tb, 0, stream>>>(Wq, Wqt);
    transposeW<<<dim3(16, 16), tb, 0, stream>>>(Wk, Wkt);
    transposeW<<<dim3(16, 16), tb, 0, stream>>>(Wv, Wvt);
    transposeW<<<dim3(16, 16), tb, 0, stream>>>(Wo, Wot);
    hipMemsetAsync(S, 0, (long)BATCH * L_SEQ * 2 * sizeof(float), stream);

    dim3 gLin(D_MODEL / BN, (BATCH * L_SEQ) / BM, 1);   // (4, 128)
    gemm_a32<<<gLin, tb, 0, stream>>>(Xq, Wqt, bq, Qf, D_MODEL, D_MODEL);
    gemm_a32<<<gLin, tb, 0, stream>>>(Xk, Wkt, bk, Kf, D_MODEL, D_MODEL);
    gemm_a32<<<gLin, tb, 0, stream>>>(Xv, Wvt, bv, Vf, D_MODEL, D_MODEL);

    fft_corr_fwd<<<dim3(512), tb, 0, stream>>>(Qf, Kf, S);
    fft_corr_inv<<<dim3(BATCH), tb, 0, stream>>>(S, raw);

    select_topk<<<1, tb, 0, stream>>>(raw, sIdx, sW);

    gather_agg<<<(BATCH * L_SEQ * D_MODEL / 8) / 256, tb, 0, stream>>>(Vf, sIdx, sW, attn);

    gemm_f16_out32<<<gLin, tb, 0, stream>>>(attn, Wot, bo, (float*)d_out, D_MODEL, D_MODEL);
}

// Round 5
// 357.867 us; speedup vs baseline: 1.7021x; 1.7021x over previous
//
#include <hip/hip_runtime.h>
#include <stdint.h>

#define BATCH 8
#define L_SEQ 2048
#define D_MODEL 512
#define TOPK 7
#define BM 128
#define BN 128
#define BK 32
#define LK 40   // LDS row stride (f16) for ds_write-staged GEMM
#define LT 136  // LDS t-stride for epilogue transpose tile (mult of 8 for uint4)

typedef _Float16 f16x8 __attribute__((ext_vector_type(8)));
typedef __attribute__((ext_vector_type(4))) float f32x4;
typedef unsigned short u16;
typedef unsigned int u32;

__device__ __forceinline__ u16 f2h(float f) {
    union { _Float16 h; u16 u; } v; v.h = (_Float16)f; return v.u;
}
__device__ __forceinline__ float h2f(u16 b) {
    union { u16 u; _Float16 h; } v; v.u = b; return (float)v.h;
}

// async 16B/lane global->LDS (m97). Dest = wave-uniform base + lane*16.
__device__ __forceinline__ void load_lds16(const u16* g, u16* l) {
    __builtin_amdgcn_global_load_lds(
        (const __attribute__((address_space(1))) u32*)(g),
        (__attribute__((address_space(3))) u32*)(l), 16, 0, 0);
}

// ---------------- fused QKV projection GEMM ----------------
// z=0: Qproj -> QT[b][d][t] (transposed)   z=1: Kproj -> KT   z=2: Vproj -> V[b][t][d]
// C = X * W^T + bias.  X: 16384 x 512 fp32 (converted to f16 in staging). Wt: 512 x 512 f16.
__global__ __launch_bounds__(256) void gemm_qkv(
    const float* __restrict__ Xq, const float* __restrict__ Xk, const float* __restrict__ Xv,
    const u16* __restrict__ Wqt, const u16* __restrict__ Wkt, const u16* __restrict__ Wvt,
    const float* __restrict__ bq, const float* __restrict__ bk, const float* __restrict__ bv,
    u16* __restrict__ QT, u16* __restrict__ KT, u16* __restrict__ Vout)
{
    __shared__ __align__(16) u16 lA[BM * LK];
    __shared__ __align__(16) u16 lB[BN * LK];
    __shared__ __align__(16) u16 lT[64 * LT];   // transpose staging (d-half x t)

    const int tid = threadIdx.x;
    const int bn = blockIdx.x, bm = blockIdx.y, z = blockIdx.z;
    const int lane = tid & 63, wave = tid >> 6;
    const int wm = wave >> 1, wn = wave & 1;
    const int l15 = lane & 15, quad = lane >> 4;

    const float* A  = (z == 0) ? Xq  : (z == 1) ? Xk  : Xv;
    const u16*   Bt = (z == 0) ? Wqt : (z == 1) ? Wkt : Wvt;
    const float* bias = (z == 0) ? bq : (z == 1) ? bk : bv;

    f32x4 acc[4][4] = {};
    const int K = D_MODEL, N = D_MODEL;

    for (int k0 = 0; k0 < K; k0 += BK) {
        #pragma unroll
        for (int j = 0; j < 4; ++j) {
            int idx = tid + j * 256;                  // 128x32 fp32 tile / 4
            int row = idx >> 3, c4 = (idx & 7) * 4;
            float4 va = *(const float4*)(A + (long)(bm * BM + row) * K + k0 + c4);
            ushort4 pa;
            pa.x = f2h(va.x); pa.y = f2h(va.y); pa.z = f2h(va.z); pa.w = f2h(va.w);
            *(ushort4*)&lA[row * LK + c4] = pa;
        }
        #pragma unroll
        for (int j = 0; j < 2; ++j) {
            int idx = tid + j * 256;                  // 128x32 f16 tile / 8
            int row = idx >> 2, c8 = (idx & 3) * 8;
            *(uint4*)&lB[row * LK + c8] =
                *(const uint4*)(Bt + (long)(bn * BN + row) * K + k0 + c8);
        }
        __syncthreads();

        f16x8 fa[4], fb[4];
        #pragma unroll
        for (int i = 0; i < 4; ++i)
            fa[i] = *(const f16x8*)&lA[(wm * 64 + i * 16 + l15) * LK + quad * 8];
        #pragma unroll
        for (int j = 0; j < 4; ++j)
            fb[j] = *(const f16x8*)&lB[(wn * 64 + j * 16 + l15) * LK + quad * 8];
        #pragma unroll
        for (int i = 0; i < 4; ++i)
            #pragma unroll
            for (int j = 0; j < 4; ++j)
                acc[i][j] = __builtin_amdgcn_mfma_f32_16x16x32_f16(fa[i], fb[j], acc[i][j], 0, 0, 0);
        __syncthreads();
    }

    if (z < 2) {
        // transposed epilogue: out[b][d][t], d = bn*128 + (h*64 + j*16 + l15)
        u16* out = (z == 0) ? QT : KT;
        const int t0 = (bm * BM) & (L_SEQ - 1);
        const int bb = (bm * BM) >> 11;
        #pragma unroll
        for (int h = 0; h < 2; ++h) {
            __syncthreads();
            if (wn == h) {
                #pragma unroll
                for (int j = 0; j < 4; ++j) {
                    int dloc = j * 16 + l15;
                    float bvv = bias[bn * BN + h * 64 + dloc];
                    #pragma unroll
                    for (int i = 0; i < 4; ++i) {
                        int trow = wm * 64 + i * 16 + quad * 4;
                        #pragma unroll
                        for (int r = 0; r < 4; ++r)
                            lT[dloc * LT + trow + r] = f2h(acc[i][j][r] + bvv);
                    }
                }
            }
            __syncthreads();
            int dloc = tid >> 2, q4 = tid & 3;
            long base = ((long)(bb * D_MODEL + bn * BN + h * 64 + dloc)) * L_SEQ + t0;
            #pragma unroll
            for (int s = 0; s < 4; ++s) {
                int c = q4 * 4 + s;
                *(uint4*)(out + base + c * 8) = *(const uint4*)&lT[dloc * LT + c * 8];
            }
        }
    } else {
        #pragma unroll
        for (int i = 0; i < 4; ++i) {
            int row = bm * BM + wm * 64 + i * 16 + quad * 4;
            #pragma unroll
            for (int j = 0; j < 4; ++j) {
                int col = bn * BN + wn * 64 + j * 16 + l15;
                float bvv = bias[col];
                #pragma unroll
                for (int r = 0; r < 4; ++r)
                    Vout[(long)(row + r) * N + col] = f2h(acc[i][j][r] + bvv);
            }
        }
    }
}

// ---------------- final projection GEMM: A f16 via global_load_lds, C fp32 ----------------
__global__ __launch_bounds__(256, 4) void gemm_f16_out32(
    const u16* __restrict__ A, const u16* __restrict__ Bt,
    const float* __restrict__ bias, float* __restrict__ Cp, int N, int K)
{
    __shared__ __align__(16) u16 lA[BM * BK];   // 8 KB, unpadded, XOR-swizzled
    __shared__ __align__(16) u16 lB[BN * BK];

    const int tid = threadIdx.x;
    const int bn = blockIdx.x, bm = blockIdx.y;
    const int lane = tid & 63, wave = tid >> 6;
    const int wm = wave >> 1, wn = wave & 1;
    const int l15 = lane & 15, quad = lane >> 4;

    const int s0 = wave * 64 + lane, s1 = s0 + 256;
    const int r0 = s0 >> 2, c0 = (s0 & 3) ^ ((r0 >> 1) & 3);
    const int r1 = s1 >> 2, c1 = (s1 & 3) ^ ((r1 >> 1) & 3);
    const u16* gA0 = A + (long)(bm * BM + r0) * K + c0 * 8;
    const u16* gA1 = A + (long)(bm * BM + r1) * K + c1 * 8;
    const u16* gB0 = Bt + (long)(bn * BN + r0) * K + c0 * 8;
    const u16* gB1 = Bt + (long)(bn * BN + r1) * K + c1 * 8;
    u16* lA0 = &lA[wave * 512]; u16* lA1 = &lA[2048 + wave * 512];
    u16* lB0 = &lB[wave * 512]; u16* lB1 = &lB[2048 + wave * 512];

    f32x4 acc[4][4] = {};

    for (int k0 = 0; k0 < K; k0 += BK) {
        load_lds16(gA0, lA0); load_lds16(gA1, lA1);
        load_lds16(gB0, lB0); load_lds16(gB1, lB1);
        gA0 += BK; gA1 += BK; gB0 += BK; gB1 += BK;
        __syncthreads();

        f16x8 fa[4], fb[4];
        #pragma unroll
        for (int i = 0; i < 4; ++i) {
            int m = wm * 64 + i * 16 + l15;
            int cs = quad ^ ((m >> 1) & 3);
            fa[i] = *(const f16x8*)&lA[m * 32 + cs * 8];
        }
        #pragma unroll
        for (int j = 0; j < 4; ++j) {
            int n = wn * 64 + j * 16 + l15;
            int cs = quad ^ ((n >> 1) & 3);
            fb[j] = *(const f16x8*)&lB[n * 32 + cs * 8];
        }
        #pragma unroll
        for (int i = 0; i < 4; ++i)
            #pragma unroll
            for (int j = 0; j < 4; ++j)
                acc[i][j] = __builtin_amdgcn_mfma_f32_16x16x32_f16(fa[i], fb[j], acc[i][j], 0, 0, 0);
        __syncthreads();
    }

    #pragma unroll
    for (int i = 0; i < 4; ++i) {
        int row = bm * BM + wm * 64 + i * 16 + quad * 4;
        #pragma unroll
        for (int j = 0; j < 4; ++j) {
            int col = bn * BN + wn * 64 + j * 16 + l15;
            float bvv = bias[col];
            #pragma unroll
            for (int r = 0; r < 4; ++r)
                Cp[(long)(row + r) * N + col] = acc[i][j][r] + bvv;
        }
    }
}

// ---------------- FFT autocorrelation (inputs in [b][d][t] layout) ----------------
// z[t] = q + i*k; one 2048-pt complex FFT per d; S[b,f] += Qhat*conj(Khat).
__global__ __launch_bounds__(256) void fft_corr_fwd(
    const u16* __restrict__ QT, const u16* __restrict__ KT, float* __restrict__ S)
{
    __shared__ float Zr[2048], Zi[2048];      // 16 KB
    __shared__ float Sr[2048], Si[2048];      // 16 KB
    __shared__ float Twr[1024], Twi[1024];    // 8 KB
    const int tid = threadIdx.x;
    const int b = blockIdx.x >> 6, dg = blockIdx.x & 63;

    #pragma unroll
    for (int j = 0; j < 4; ++j) {
        int i = tid + j * 256;
        float ang = -6.28318530717958647692f * (float)i * (1.0f / 2048.0f);
        float sn, cs; __sincosf(ang, &sn, &cs);
        Twr[i] = cs; Twi[i] = sn;
    }
    #pragma unroll
    for (int j = 0; j < 8; ++j) { Sr[tid + j * 256] = 0.f; Si[tid + j * 256] = 0.f; }

    for (int g = 0; g < 8; ++g) {
        int d = dg * 8 + g;
        const u16* qrow = QT + ((long)b * D_MODEL + d) * L_SEQ;
        const u16* krow = KT + ((long)b * D_MODEL + d) * L_SEQ;
        __syncthreads();   // Z reuse guard
        union { uint4 u; _Float16 h[8]; } xq, xk;
        xq.u = *(const uint4*)(qrow + tid * 8);
        xk.u = *(const uint4*)(krow + tid * 8);
        #pragma unroll
        for (int j = 0; j < 8; ++j) {
            int t = tid * 8 + j;
            int tr = (int)(__brev((unsigned)t) >> 21);   // 11-bit reversal
            Zr[tr] = (float)xq.h[j];
            Zi[tr] = (float)xk.h[j];
        }
        __syncthreads();
        for (int s = 0; s < 11; ++s) {
            #pragma unroll
            for (int j = 0; j < 4; ++j) {
                int idx = tid + j * 256;
                int pos = idx & ((1 << s) - 1);
                int i0 = ((idx >> s) << (s + 1)) + pos;
                int i1 = i0 + (1 << s);
                float wr = Twr[pos << (10 - s)], wi = Twi[pos << (10 - s)];
                float ar = Zr[i0], ai = Zi[i0];
                float br = Zr[i1], bi = Zi[i1];
                float tr_ = br * wr - bi * wi;
                float ti_ = br * wi + bi * wr;
                Zr[i0] = ar + tr_; Zi[i0] = ai + ti_;
                Zr[i1] = ar - tr_; Zi[i1] = ai - ti_;
            }
            __syncthreads();
        }
        #pragma unroll
        for (int j = 0; j < 8; ++j) {
            int f = tid + j * 256;
            int fm = (2048 - f) & 2047;
            float Xr = Zr[f], Xi = Zi[f], Xmr = Zr[fm], Xmi = Zi[fm];
            float qr = 0.5f * (Xr + Xmr), qi = 0.5f * (Xi - Xmi);   // Qhat
            float dr = Xr - Xmr,          di = Xi + Xmi;
            float kr = 0.5f * di,         ki = -0.5f * dr;          // Khat
            Sr[f] += qr * kr + qi * ki;                             // Qhat*conj(Khat)
            Si[f] += qi * kr - qr * ki;
        }
    }
    __syncthreads();
    #pragma unroll
    for (int j = 0; j < 8; ++j) {
        int f = tid + j * 256;
        atomicAdd(&S[((long)b * 2048 + f) * 2 + 0], Sr[f]);
        atomicAdd(&S[((long)b * 2048 + f) * 2 + 1], Si[f]);
    }
}

// raw[b][tau] = (1/2048) * Re( IFFT(S[b]) )  — one block per b
__global__ __launch_bounds__(256) void fft_corr_inv(
    const float* __restrict__ S, float* __restrict__ raw)
{
    __shared__ float Zr[2048], Zi[2048];
    __shared__ float Twr[1024], Twi[1024];
    const int tid = threadIdx.x;
    const int b = blockIdx.x;

    #pragma unroll
    for (int j = 0; j < 4; ++j) {
        int i = tid + j * 256;
        float ang = 6.28318530717958647692f * (float)i * (1.0f / 2048.0f);
        float sn, cs; __sincosf(ang, &sn, &cs);
        Twr[i] = cs; Twi[i] = sn;
    }
    #pragma unroll
    for (int j = 0; j < 8; ++j) {
        int f = tid + j * 256;
        int fr = (int)(__brev((unsigned)f) >> 21);
        Zr[fr] = S[((long)b * 2048 + f) * 2 + 0];
        Zi[fr] = S[((long)b * 2048 + f) * 2 + 1];
    }
    __syncthreads();
    for (int s = 0; s < 11; ++s) {
        #pragma unroll
        for (int j = 0; j < 4; ++j) {
            int idx = tid + j * 256;
            int pos = idx & ((1 << s) - 1);
            int i0 = ((idx >> s) << (s + 1)) + pos;
            int i1 = i0 + (1 << s);
            float wr = Twr[pos << (10 - s)], wi = Twi[pos << (10 - s)];
            float ar = Zr[i0], ai = Zi[i0];
            float br = Zr[i1], bi = Zi[i1];
            float tr_ = br * wr - bi * wi;
            float ti_ = br * wi + bi * wr;
            Zr[i0] = ar + tr_; Zi[i0] = ai + ti_;
            Zr[i1] = ar - tr_; Zi[i1] = ai - ti_;
        }
        __syncthreads();
    }
    #pragma unroll
    for (int j = 0; j < 8; ++j) {
        int t = tid + j * 256;
        raw[(long)b * 2048 + t] = Zr[t] * (1.0f / 2048.0f);
    }
}

// Wt[n][k] = W[k][n], fp32 -> fp16
__global__ __launch_bounds__(256) void transposeW(const float* __restrict__ src, u16* __restrict__ dst)
{
    __shared__ float t[32][33];
    int tx = threadIdx.x & 31, ty = threadIdx.x >> 5;
    int c0 = blockIdx.x * 32, r0 = blockIdx.y * 32;
    #pragma unroll
    for (int r = ty; r < 32; r += 8)
        t[r][tx] = src[(long)(r0 + r) * D_MODEL + c0 + tx];
    __syncthreads();
    #pragma unroll
    for (int r = ty; r < 32; r += 8)
        dst[(long)(c0 + r) * D_MODEL + r0 + tx] = f2h(t[tx][r]);
}

// One block. g[tau] = sum_b raw[b][tau]; top-7; per-b softmax of raw[b][idx]/512.
__global__ __launch_bounds__(256) void select_topk(
    const float* __restrict__ raw, int* __restrict__ selIdx, float* __restrict__ selW)
{
    __shared__ float g[L_SEQ];
    __shared__ float rv[256];
    __shared__ int   ri[256];
    __shared__ int   sidx[TOPK];
    __shared__ float wbuf[BATCH][TOPK];
    int tid = threadIdx.x;
    for (int t = tid; t < L_SEQ; t += 256) {
        float s = 0.0f;
        #pragma unroll
        for (int b = 0; b < BATCH; ++b) s += raw[b * L_SEQ + t];
        g[t] = s;
    }
    __syncthreads();
    for (int it = 0; it < TOPK; ++it) {
        float best = -1e30f; int bi = 0x7fffffff;
        for (int t = tid; t < L_SEQ; t += 256) {
            float v = g[t];
            if (v > best || (v == best && t < bi)) { best = v; bi = t; }
        }
        rv[tid] = best; ri[tid] = bi;
        __syncthreads();
        for (int s = 128; s > 0; s >>= 1) {
            if (tid < s) {
                float v2 = rv[tid + s]; int i2 = ri[tid + s];
                if (v2 > rv[tid] || (v2 == rv[tid] && i2 < ri[tid])) { rv[tid] = v2; ri[tid] = i2; }
            }
            __syncthreads();
        }
        if (tid == 0) { sidx[it] = ri[0]; g[ri[0]] = -1e30f; }
        __syncthreads();
    }
    if (tid < BATCH * TOPK) {
        int b = tid / TOPK, k = tid % TOPK;
        wbuf[b][k] = raw[b * L_SEQ + sidx[k]] * (1.0f / 512.0f);
    }
    __syncthreads();
    if (tid < BATCH) {
        float mx = -1e30f;
        #pragma unroll
        for (int k = 0; k < TOPK; ++k) mx = fmaxf(mx, wbuf[tid][k]);
        float e[TOPK]; float sum = 0.0f;
        #pragma unroll
        for (int k = 0; k < TOPK; ++k) { e[k] = expf(wbuf[tid][k] - mx); sum += e[k]; }
        #pragma unroll
        for (int k = 0; k < TOPK; ++k) selW[tid * TOPK + k] = e[k] / sum;
    }
    if (tid < TOPK) selIdx[tid] = sidx[tid];
}

// attn[b,l,:] = sum_k w[b][k] * V[b,(l+idx[k])%L,:]  (f16 in/out, 8 elems/thread)
__global__ __launch_bounds__(256) void gather_agg(
    const u16* __restrict__ V, const int* __restrict__ selIdx,
    const float* __restrict__ selW, u16* __restrict__ outB)
{
    __shared__ int si[TOPK];
    __shared__ float sw[TOPK];
    long flat = (long)blockIdx.x * 256 + threadIdx.x;     // over B*L*D/8 uint4s
    int b  = (int)(flat >> 17);
    int l  = (int)((flat >> 6) & (L_SEQ - 1));
    int d8 = (int)(flat & 63);
    if (threadIdx.x < TOPK) {
        si[threadIdx.x] = selIdx[threadIdx.x];
        sw[threadIdx.x] = selW[b * TOPK + threadIdx.x];
    }
    __syncthreads();
    const uint4* v8 = (const uint4*)(V + (long)b * L_SEQ * D_MODEL);
    float a[8] = {0,0,0,0,0,0,0,0};
    #pragma unroll
    for (int k = 0; k < TOPK; ++k) {
        int src = (l + si[k]) & (L_SEQ - 1);
        union { uint4 u; _Float16 h[8]; } x;
        x.u = v8[src * 64 + d8];
        float w = sw[k];
        #pragma unroll
        for (int q = 0; q < 8; ++q) a[q] += w * (float)x.h[q];
    }
    union { uint4 u; _Float16 h[8]; } o;
    #pragma unroll
    for (int q = 0; q < 8; ++q) o.h[q] = (_Float16)a[q];
    ((uint4*)outB)[flat] = o.u;
}

extern "C" void kernel_launch(void* const* d_in, const int* in_sizes, int n_in,
                              void* d_out, int out_size, void* d_ws, size_t ws_size,
                              hipStream_t stream)
{
    (void)in_sizes; (void)n_in; (void)out_size; (void)ws_size;
    const float* Xq = (const float*)d_in[0];
    const float* Xk = (const float*)d_in[1];
    const float* Xv = (const float*)d_in[2];
    const float* Wq = (const float*)d_in[3];
    const float* bq = (const float*)d_in[4];
    const float* Wk = (const float*)d_in[5];
    const float* bk = (const float*)d_in[6];
    const float* Wv = (const float*)d_in[7];
    const float* bv = (const float*)d_in[8];
    const float* Wo = (const float*)d_in[9];
    const float* bo = (const float*)d_in[10];

    char* ws = (char*)d_ws;
    const long SLABH = (long)BATCH * L_SEQ * D_MODEL * sizeof(u16);   // 16 MB
    u16* QT   = (u16*)(ws);                    // [b][d][t]
    u16* KT   = (u16*)(ws + SLABH);            // [b][d][t]
    u16* Vf   = (u16*)(ws + 2 * SLABH);        // [b][t][d]
    u16* attn = (u16*)(ws + 3 * SLABH);
    const long WSZ = (long)D_MODEL * D_MODEL;
    u16* Wt   = (u16*)(ws + 4 * SLABH);        // 4 x 512 KB
    u16* Wqt = Wt + 0 * WSZ; u16* Wkt = Wt + 1 * WSZ;
    u16* Wvt = Wt + 2 * WSZ; u16* Wot = Wt + 3 * WSZ;
    float* S   = (float*)(ws + 4 * SLABH + 4 * WSZ * sizeof(u16));   // 8*2048*2 fp32
    float* raw = S + (long)BATCH * L_SEQ * 2;
    int*   sIdx = (int*)(raw + (long)BATCH * L_SEQ);
    float* sW   = (float*)(sIdx + 8);

    dim3 tb(256);
    transposeW<<<dim3(16, 16), tb, 0, stream>>>(Wq, Wqt);
    transposeW<<<dim3(16, 16), tb, 0, stream>>>(Wk, Wkt);
    transposeW<<<dim3(16, 16), tb, 0, stream>>>(Wv, Wvt);
    transposeW<<<dim3(16, 16), tb, 0, stream>>>(Wo, Wot);
    hipMemsetAsync(S, 0, (long)BATCH * L_SEQ * 2 * sizeof(float), stream);

    // fused Q/K/V projections (z-batched), Q/K written transposed
    dim3 gP(D_MODEL / BN, (BATCH * L_SEQ) / BM, 3);   // (4, 128, 3)
    gemm_qkv<<<gP, tb, 0, stream>>>(Xq, Xk, Xv, Wqt, Wkt, Wvt, bq, bk, bv, QT, KT, Vf);

    fft_corr_fwd<<<dim3(512), tb, 0, stream>>>(QT, KT, S);
    fft_corr_inv<<<dim3(BATCH), tb, 0, stream>>>(S, raw);

    select_topk<<<1, tb, 0, stream>>>(raw, sIdx, sW);

    gather_agg<<<(BATCH * L_SEQ * D_MODEL / 8) / 256, tb, 0, stream>>>(Vf, sIdx, sW, attn);

    dim3 gO(D_MODEL / BN, (BATCH * L_SEQ) / BM, 1);
    gemm_f16_out32<<<gO, tb, 0, stream>>>(attn, Wot, bo, (float*)d_out, D_MODEL, D_MODEL);
}